// Round 1
// baseline (100.161 us; speedup 1.0000x reference)
//
#include <hip/hip_runtime.h>

typedef unsigned short u16;
typedef __attribute__((ext_vector_type(4))) float f32x4;
typedef __attribute__((ext_vector_type(8))) short bf16x8;
typedef __attribute__((ext_vector_type(8))) unsigned short u16x8;

#define QN 512
#define SN 128
#define TN 16
#define DN 512
#define QT (QN*TN)   /* 8192 query frames */
#define STF (SN*TN)  /* 2048 support frames */

#if __has_builtin(__builtin_amdgcn_exp2f)
#define EXP2F __builtin_amdgcn_exp2f
#else
#define EXP2F exp2f
#endif
#if __has_builtin(__builtin_amdgcn_logf)
#define LOG2F __builtin_amdgcn_logf
#else
#define LOG2F log2f
#endif

#define KEXP 2.8853900817779268f   /* 1/(lbda*ln2), lbda=0.5 */
#define CLOG 0.34657359027997264f  /* lbda*ln2 */

__device__ __forceinline__ u16 f2bf(float f){
  union { float f; unsigned int u; } v; v.f = f;
  unsigned int u = v.u;
  unsigned int r = (u + 0x7fffu + ((u >> 16) & 1u)) >> 16;
  return (u16)r;
}

// ---------------- prep: f32 -> bf16 convert + row norms ----------------
__global__ __launch_bounds__(256) void prep_kernel(
    const float* __restrict__ sup, const float* __restrict__ tgt,
    u16* __restrict__ Abf, u16* __restrict__ Bbf,
    float* __restrict__ nx, float* __restrict__ ny)
{
  int w = (int)((blockIdx.x * blockDim.x + threadIdx.x) >> 6);
  int lane = threadIdx.x & 63;
  if (w >= QT + STF) return;
  bool isQ = (w < QT);
  int row = isQ ? w : (w - QT);
  const float* src = (isQ ? tgt : sup) + (size_t)row * DN + lane * 8;
  f32x4 x0 = *(const f32x4*)src;
  f32x4 x1 = *(const f32x4*)(src + 4);
  float ss = 0.f;
  #pragma unroll
  for (int i = 0; i < 4; ++i) { ss += x0[i]*x0[i]; ss += x1[i]*x1[i]; }
  u16x8 o;
  #pragma unroll
  for (int i = 0; i < 4; ++i) { o[i] = f2bf(x0[i]); o[i+4] = f2bf(x1[i]); }
  u16* dst = (isQ ? Abf : Bbf) + (size_t)row * DN + lane * 8;
  *(u16x8*)dst = o;
  #pragma unroll
  for (int off = 32; off; off >>= 1) ss += __shfl_xor(ss, off);
  if (lane == 0) (isQ ? nx : ny)[row] = sqrtf(ss);
}

// ---------------- gemm: bf16 MFMA, epilogue -> dists + distsT ----------------
__global__ __launch_bounds__(256) void gemm_kernel(
    const u16* __restrict__ Abf, const u16* __restrict__ Bbf,
    const float* __restrict__ nx, const float* __restrict__ ny,
    float* __restrict__ dists, float* __restrict__ distsT, int q0)
{
  __shared__ u16 As[128][40];  // +8 pad (16B) to break bank conflicts
  __shared__ u16 Bs[128][40];
  const int t = threadIdx.x;
  const int m0 = q0 * TN + blockIdx.y * 128;   // global query-frame row base
  const int n0 = blockIdx.x * 128;             // global support-frame col base
  const int wave = t >> 6, lane = t & 63;
  const int wr = wave >> 1, wc = wave & 1;
  const int lhi = lane >> 4, llo = lane & 15;

  f32x4 acc[4][4] = {};

  const int rowA = t >> 1, seg = t & 1;
  const u16* gA = Abf + (size_t)(m0 + rowA) * DN + seg * 16;
  const u16* gB = Bbf + (size_t)(n0 + rowA) * DN + seg * 16;

  for (int k0 = 0; k0 < DN; k0 += 32) {
    u16x8 a0 = *(const u16x8*)(gA + k0);
    u16x8 a1 = *(const u16x8*)(gA + k0 + 8);
    u16x8 b0 = *(const u16x8*)(gB + k0);
    u16x8 b1 = *(const u16x8*)(gB + k0 + 8);
    __syncthreads();
    *(u16x8*)&As[rowA][seg*16]     = a0;
    *(u16x8*)&As[rowA][seg*16 + 8] = a1;
    *(u16x8*)&Bs[rowA][seg*16]     = b0;
    *(u16x8*)&Bs[rowA][seg*16 + 8] = b1;
    __syncthreads();

    bf16x8 af[4], bfr[4];
    #pragma unroll
    for (int mi = 0; mi < 4; ++mi)
      af[mi] = *(const bf16x8*)&As[wr*64 + mi*16 + llo][lhi*8];
    #pragma unroll
    for (int ni = 0; ni < 4; ++ni)
      bfr[ni] = *(const bf16x8*)&Bs[wc*64 + ni*16 + llo][lhi*8];
    #pragma unroll
    for (int mi = 0; mi < 4; ++mi)
      #pragma unroll
      for (int ni = 0; ni < 4; ++ni)
        acc[mi][ni] = __builtin_amdgcn_mfma_f32_16x16x32_bf16(af[mi], bfr[ni], acc[mi][ni], 0, 0, 0);
  }

  // epilogue: dist = 1 - dot/(nx*ny+eps); scatter to both layouts
  #pragma unroll
  for (int mi = 0; mi < 4; ++mi) {
    #pragma unroll
    for (int ni = 0; ni < 4; ++ni) {
      int gcol = n0 + wc*64 + ni*16 + llo;
      float nyv = ny[gcol];
      int s = gcol >> 4, ts = gcol & 15;
      #pragma unroll
      for (int j = 0; j < 4; ++j) {
        int grow = m0 + wr*64 + mi*16 + lhi*4 + j;
        float den = nx[grow] * nyv + 0.01f;
        float v = 1.0f - acc[mi][ni][j] / den;
        int qloc = (grow >> 4) - q0;
        int tq = grow & 15;
        size_t pair = (size_t)qloc * SN + s;
        dists [pair*256 + tq*16 + ts] = v;
        distsT[pair*256 + ts*16 + tq] = v;
      }
    }
  }
}

// ---------------- otam DP: one lane per (q,s), both directions interleaved ----------------
__device__ __forceinline__ float softmin2(float p, float c){
  float mn = fminf(p, c);
  float s = 1.0f + EXP2F(-fabsf(p - c) * KEXP);
  return mn - CLOG * LOG2F(s);
}
__device__ __forceinline__ float softmin3(float p, float c, float ex){
  float mn = fminf(fminf(p, c), ex);
  float s = EXP2F((mn - p) * KEXP) + EXP2F((mn - c) * KEXP) + EXP2F((mn - ex) * KEXP);
  return mn - CLOG * LOG2F(s);
}

#define LOAD16(dr, base, l) { \
  const f32x4* _p = (const f32x4*)((base) + (size_t)(l) * 16); \
  f32x4 _v0 = _p[0], _v1 = _p[1], _v2 = _p[2], _v3 = _p[3]; \
  dr[0]=_v0[0]; dr[1]=_v0[1]; dr[2]=_v0[2]; dr[3]=_v0[3]; \
  dr[4]=_v1[0]; dr[5]=_v1[1]; dr[6]=_v1[2]; dr[7]=_v1[3]; \
  dr[8]=_v2[0]; dr[9]=_v2[1]; dr[10]=_v2[2]; dr[11]=_v2[3]; \
  dr[12]=_v3[0]; dr[13]=_v3[1]; dr[14]=_v3[2]; dr[15]=_v3[3]; }

__global__ __launch_bounds__(256) void otam_kernel(
    const float* __restrict__ dists, const float* __restrict__ distsT,
    float* __restrict__ out, int q0, int nPairs)
{
  int idx = blockIdx.x * 256 + threadIdx.x;
  if (idx >= nPairs) return;
  const float* t0 = dists  + (size_t)idx * 256;
  const float* t1 = distsT + (size_t)idx * 256;

  float p0[18], p1[18];
  {
    float dr0[16], dr1[16];
    LOAD16(dr0, t0, 0); LOAD16(dr1, t1, 0);
    p0[0] = 0.f; p1[0] = 0.f;
    float a0 = 0.f, a1 = 0.f;
    #pragma unroll
    for (int m = 1; m <= 16; ++m) { a0 += dr0[m-1]; p0[m] = a0; a1 += dr1[m-1]; p1[m] = a1; }
    p0[17] = a0; p1[17] = a1;
  }
  for (int l = 1; l < 16; ++l) {
    float dr0[16], dr1[16];
    LOAD16(dr0, t0, l); LOAD16(dr1, t1, l);
    float c0 = 0.f, c1 = 0.f;
    float n0_[18], n1_[18];
    n0_[0] = 0.f; n1_[0] = 0.f;
    #pragma unroll
    for (int m = 1; m <= 17; ++m) {
      float d0 = (m <= 16) ? dr0[m-1] : 0.f;
      float d1 = (m <= 16) ? dr1[m-1] : 0.f;
      float v0, v1;
      if (m == 1)       { v0 = d0 + softmin3(p0[0],  c0, p0[1]);  v1 = d1 + softmin3(p1[0],  c1, p1[1]); }
      else if (m == 17) { v0 = d0 + softmin3(p0[16], c0, p0[17]); v1 = d1 + softmin3(p1[16], c1, p1[17]); }
      else              { v0 = d0 + softmin2(p0[m-1], c0);        v1 = d1 + softmin2(p1[m-1], c1); }
      n0_[m] = v0; c0 = v0;
      n1_[m] = v1; c1 = v1;
    }
    #pragma unroll
    for (int m = 0; m < 18; ++m) { p0[m] = n0_[m]; p1[m] = n1_[m]; }
  }
  int q = idx >> 7, s2 = idx & 127;
  out[(size_t)(q0 + q) * SN + s2] = p0[17] + p1[17];
}

// ---------------- launch ----------------
extern "C" void kernel_launch(void* const* d_in, const int* in_sizes, int n_in,
                              void* d_out, int out_size, void* d_ws, size_t ws_size,
                              hipStream_t stream)
{
  const float* sup = (const float*)d_in[0];  // [128,16,512]
  const float* tgt = (const float*)d_in[1];  // [512,16,512]
  float* out = (float*)d_out;                // [512,128]
  char* ws = (char*)d_ws;

  const size_t offA  = 0;                       // A bf16: 8192*512*2 = 8,388,608
  const size_t offB  = 8388608;                 // B bf16: 2048*512*2 = 2,097,152
  const size_t offNx = 10485760;                // nx: 8192*4
  const size_t offNy = 10518528;                // ny: 2048*4
  const size_t offD  = 10526720;                // dists chunks (256B aligned)

  u16* Abf = (u16*)(ws + offA);
  u16* Bbf = (u16*)(ws + offB);
  float* nx = (float*)(ws + offNx);
  float* ny = (float*)(ws + offNy);
  char* dbase = ws + offD;

  size_t avail = (ws_size > offD) ? (ws_size - offD) : 0;
  long long cqll = (long long)(avail / (2ull * 131072ull));  // bytes per query (both layouts)
  int chunkQ = (int)(cqll > 512 ? 512 : cqll);
  chunkQ &= ~7;
  if (chunkQ < 8) chunkQ = 8;

  prep_kernel<<<dim3((QT + STF) / 4), dim3(256), 0, stream>>>(sup, tgt, Abf, Bbf, nx, ny);

  for (int q0 = 0; q0 < QN; q0 += chunkQ) {
    int cq = (QN - q0 < chunkQ) ? (QN - q0) : chunkQ;
    float* dists  = (float*)dbase;
    float* distsT = (float*)(dbase + (size_t)cq * 131072ull);
    gemm_kernel<<<dim3(STF / 128, cq / 8), dim3(256), 0, stream>>>(Abf, Bbf, nx, ny, dists, distsT, q0);
    otam_kernel<<<dim3(cq * SN / 256), dim3(256), 0, stream>>>(dists, distsT, out, q0, cq * SN);
  }
}

// Round 3
// 53.539 us; speedup vs baseline: 1.8708x; 1.8708x over previous
//
#include <hip/hip_runtime.h>

typedef unsigned short u16;
typedef __attribute__((ext_vector_type(4))) unsigned short u16x4;
typedef __attribute__((ext_vector_type(8))) unsigned short u16x8;
typedef __attribute__((ext_vector_type(8))) short bf16x8;
typedef __attribute__((ext_vector_type(4))) float f32x4;

#define QN 512
#define SN 128
#define TN 16
#define DN 512
#define QT (QN*TN)   /* 8192 query frames */
#define STF (SN*TN)  /* 2048 support frames */

#if __has_builtin(__builtin_amdgcn_exp2f)
#define EXP2F __builtin_amdgcn_exp2f
#else
#define EXP2F exp2f
#endif
#if __has_builtin(__builtin_amdgcn_logf)
#define LOG2F __builtin_amdgcn_logf
#else
#define LOG2F log2f
#endif

#define KEXP 2.8853900817779268f   /* 1/(lbda*ln2), lbda=0.5 */
#define CLOG 0.34657359027997264f  /* lbda*ln2 */
#define K2   7.38905609893065f     /* exp(1/lbda) = e^2, per-row rescale */

__device__ __forceinline__ u16 f2bf(float f){
  union { float f; unsigned int u; } v; v.f = f;
  unsigned int u = v.u;
  unsigned int r = (u + 0x7fffu + ((u >> 16) & 1u)) >> 16;
  return (u16)r;
}
__device__ __forceinline__ float bf2f(u16 v){
  union { unsigned int u; float f; } x; x.u = ((unsigned int)v) << 16; return x.f;
}

// ---------------- prep: f32 -> bf16 convert + row norms ----------------
__global__ __launch_bounds__(256) void prep_kernel(
    const float* __restrict__ sup, const float* __restrict__ tgt,
    u16* __restrict__ Abf, u16* __restrict__ Bbf,
    float* __restrict__ nx, float* __restrict__ ny)
{
  int w = (int)((blockIdx.x * blockDim.x + threadIdx.x) >> 6);
  int lane = threadIdx.x & 63;
  if (w >= QT + STF) return;
  bool isQ = (w < QT);
  int row = isQ ? w : (w - QT);
  const float* src = (isQ ? tgt : sup) + (size_t)row * DN + lane * 8;
  f32x4 x0 = *(const f32x4*)src;
  f32x4 x1 = *(const f32x4*)(src + 4);
  float ss = 0.f;
  #pragma unroll
  for (int i = 0; i < 4; ++i) { ss += x0[i]*x0[i]; ss += x1[i]*x1[i]; }
  u16x8 o;
  #pragma unroll
  for (int i = 0; i < 4; ++i) { o[i] = f2bf(x0[i]); o[i+4] = f2bf(x1[i]); }
  u16* dst = (isQ ? Abf : Bbf) + (size_t)row * DN + lane * 8;
  *(u16x8*)dst = o;
  #pragma unroll
  for (int off = 32; off; off >>= 1) ss += __shfl_xor(ss, off);
  if (lane == 0) (isQ ? nx : ny)[row] = sqrtf(ss);
}

// ---------------- fused: MFMA GEMM -> LDS ed-tiles -> exp-domain OTAM DP ----------------
// tile: 128 query-frames (8 queries) x 128 support-frames (8 supports)
// => 64 (q,s) pairs x 2 directions = 128 DP tasks x 512B = 65536B LDS exactly.
// dt holds ed = exp(-d/lbda) as bf16, 16B-granule XOR swizzle ((task&31)<<4).
__global__ __launch_bounds__(256, 2) void fused_kernel(
    const u16* __restrict__ Abf, const u16* __restrict__ Bbf,
    const float* __restrict__ nx, const float* __restrict__ ny,
    float* __restrict__ out)
{
  __shared__ __align__(128) char smem[65536];
  u16 (*As)[40] = (u16(*)[40])smem;             // [128][40]
  u16 (*Bs)[40] = (u16(*)[40])(smem + 10240);   // [128][40]

  const int t = threadIdx.x;
  const int m0 = blockIdx.y * 128;   // query-frame base
  const int n0 = blockIdx.x * 128;   // support-frame base
  const int wave = t >> 6, lane = t & 63;
  const int wr = wave >> 1, wc = wave & 1;
  const int lhi = lane >> 4, llo = lane & 15;

  f32x4 acc[4][4] = {};

  const int rowA = t >> 1, segA = t & 1;
  const u16* gA = Abf + (size_t)(m0 + rowA) * DN + segA * 16;
  const u16* gB = Bbf + (size_t)(n0 + rowA) * DN + segA * 16;

  for (int k0 = 0; k0 < DN; k0 += 32) {
    u16x8 a0 = *(const u16x8*)(gA + k0);
    u16x8 a1 = *(const u16x8*)(gA + k0 + 8);
    u16x8 b0 = *(const u16x8*)(gB + k0);
    u16x8 b1 = *(const u16x8*)(gB + k0 + 8);
    __syncthreads();
    *(u16x8*)&As[rowA][segA*16]     = a0;
    *(u16x8*)&As[rowA][segA*16 + 8] = a1;
    *(u16x8*)&Bs[rowA][segA*16]     = b0;
    *(u16x8*)&Bs[rowA][segA*16 + 8] = b1;
    __syncthreads();

    bf16x8 af[4], bfr[4];
    #pragma unroll
    for (int mi = 0; mi < 4; ++mi)
      af[mi] = *(const bf16x8*)&As[wr*64 + mi*16 + llo][lhi*8];
    #pragma unroll
    for (int ni = 0; ni < 4; ++ni)
      bfr[ni] = *(const bf16x8*)&Bs[wc*64 + ni*16 + llo][lhi*8];
    #pragma unroll
    for (int mi = 0; mi < 4; ++mi)
      #pragma unroll
      for (int ni = 0; ni < 4; ++ni)
        acc[mi][ni] = __builtin_amdgcn_mfma_f32_16x16x32_bf16(af[mi], bfr[ni], acc[mi][ni], 0, 0, 0);
  }
  __syncthreads();  // staging LDS reads done; smem about to be reused as dt

  // ---- epilogue: ed = exp2((acc*rcp(den) - 1)*KEXP), write both orientations ----
  float nxv[4][4];
  #pragma unroll
  for (int mi = 0; mi < 4; ++mi)
    #pragma unroll
    for (int j = 0; j < 4; ++j)
      nxv[mi][j] = nx[m0 + wr*64 + mi*16 + lhi*4 + j];

  #pragma unroll
  for (int ni = 0; ni < 4; ++ni) {
    int gcol = n0 + wc*64 + ni*16 + llo;
    float nyv = ny[gcol];
    int sloc = wc*4 + ni;
    int ts = llo;
    #pragma unroll
    for (int mi = 0; mi < 4; ++mi) {
      int qloc = wr*4 + mi;
      int t0 = (qloc*8 + sloc) * 2;   // dir-0 task
      int t1 = t0 + 1;                // dir-1 task (transposed)
      int swz0 = (t0 & 31) << 4, swz1 = (t1 & 31) << 4;
      u16x4 pk;
      #pragma unroll
      for (int j = 0; j < 4; ++j) {
        int tq = lhi*4 + j;
        float den = nxv[mi][j] * nyv + 0.01f;
        float r = __builtin_amdgcn_rcpf(den);
        float ed = EXP2F(fmaf(acc[mi][ni][j] * r, KEXP, -KEXP));
        u16 e16 = f2bf(ed);
        pk[j] = e16;
        // dir0: element (l=tq, m=ts)
        *(u16*)(smem + t0*512 + ((tq*32 + ts*2) ^ swz0)) = e16;
      }
      // dir1: elements (l=ts, m=tq), 4 consecutive tq packed -> 8B store
      *(u16x4*)(smem + t1*512 + ((ts*32 + lhi*8) ^ swz1)) = pk;
    }
  }
  __syncthreads();

  // ---- exp-domain DP, one task per thread (threads 0..127) ----
  if (t < 128) {
    const char* tb = smem + t * 512;
    const int swz = (t & 31) << 4;
    float F[18];
    {
      u16x8 g0 = *(const u16x8*)(tb + (0 ^ swz));
      u16x8 g1 = *(const u16x8*)(tb + (16 ^ swz));
      float c = 1.0f;
      F[0] = 1.0f;
      #pragma unroll
      for (int m = 1; m <= 8; ++m)  { c *= bf2f(g0[m-1]); F[m] = c; }
      #pragma unroll
      for (int m = 9; m <= 16; ++m) { c *= bf2f(g1[m-9]); F[m] = c; }
      F[17] = c;
    }
    // prefetch row 1
    u16x8 h0 = *(const u16x8*)(tb + (32 ^ swz));
    u16x8 h1 = *(const u16x8*)(tb + (48 ^ swz));
    float rowc = 1.0f;
    #pragma unroll 1
    for (int l = 1; l < 16; ++l) {
      u16x8 n0v, n1v;
      if (l < 15) {
        n0v = *(const u16x8*)(tb + (((l+1)*32) ^ swz));
        n1v = *(const u16x8*)(tb + (((l+1)*32 + 16) ^ swz));
      }
      rowc *= K2;
      float pm1 = F[0];      // old F[l-1][0]
      F[0] = rowc;           // cum[l][0] = 0  ->  exp(B_l/lbda)
      {
        float pm = F[1];
        F[1] = bf2f(h0[0]) * (F[0] + pm1*K2 + pm*K2);  // edge m=1: 3 preds
        pm1 = pm;
      }
      #pragma unroll
      for (int m = 2; m <= 8; ++m) {
        float pm = F[m];
        F[m] = bf2f(h0[m-1]) * (F[m-1] + pm1*K2);
        pm1 = pm;
      }
      #pragma unroll
      for (int m = 9; m <= 16; ++m) {
        float pm = F[m];
        F[m] = bf2f(h1[m-9]) * (F[m-1] + pm1*K2);
        pm1 = pm;
      }
      F[17] = F[16] + pm1*K2 + F[17]*K2;  // edge m=17: 3 preds, d_pad=0 -> ed=1
      h0 = n0v; h1 = n1v;
    }
    float res = 15.0f - CLOG * LOG2F(F[17]);
    float other = __shfl_xor(res, 1);
    if (!(t & 1)) {
      int pair = t >> 1, qloc = pair >> 3, sloc = pair & 7;
      out[(size_t)(blockIdx.y*8 + qloc) * SN + blockIdx.x*8 + sloc] = res + other;
    }
  }
}

// ---------------- launch ----------------
extern "C" void kernel_launch(void* const* d_in, const int* in_sizes, int n_in,
                              void* d_out, int out_size, void* d_ws, size_t ws_size,
                              hipStream_t stream)
{
  const float* sup = (const float*)d_in[0];  // [128,16,512]
  const float* tgt = (const float*)d_in[1];  // [512,16,512]
  float* out = (float*)d_out;                // [512,128]
  char* ws = (char*)d_ws;

  u16* Abf = (u16*)(ws);                     // 8192*512*2  = 8,388,608
  u16* Bbf = (u16*)(ws + 8388608);           // 2048*512*2  = 2,097,152
  float* nx = (float*)(ws + 10485760);       // 8192*4
  float* ny = (float*)(ws + 10518528);       // 2048*4

  prep_kernel<<<dim3((QT + STF) / 4), dim3(256), 0, stream>>>(sup, tgt, Abf, Bbf, nx, ny);
  fused_kernel<<<dim3(STF/128, QT/128), dim3(256), 0, stream>>>(Abf, Bbf, nx, ny, out);
}

// Round 4
// 45.000 us; speedup vs baseline: 2.2258x; 1.1898x over previous
//
#include <hip/hip_runtime.h>

typedef unsigned short u16;
typedef __attribute__((ext_vector_type(4))) unsigned short u16x4;
typedef __attribute__((ext_vector_type(8))) unsigned short u16x8;
typedef __attribute__((ext_vector_type(8))) short bf16x8;
typedef __attribute__((ext_vector_type(4))) float f32x4;

#define QN 512
#define SN 128
#define TN 16
#define DN 512
#define QT (QN*TN)   /* 8192 query frames */
#define STF (SN*TN)  /* 2048 support frames */

#if __has_builtin(__builtin_amdgcn_exp2f)
#define EXP2F __builtin_amdgcn_exp2f
#else
#define EXP2F exp2f
#endif
#if __has_builtin(__builtin_amdgcn_logf)
#define LOG2F __builtin_amdgcn_logf
#else
#define LOG2F log2f
#endif

#define KEXP 2.8853900817779268f   /* 1/(lbda*ln2), lbda=0.5 */
#define CLOG 0.34657359027997264f  /* lbda*ln2 */
#define K2   7.38905609893065f     /* exp(1/lbda) = e^2, per-row rescale */

__device__ __forceinline__ u16 f2bf(float f){
  union { float f; unsigned int u; } v; v.f = f;
  unsigned int u = v.u;
  unsigned int r = (u + 0x7fffu + ((u >> 16) & 1u)) >> 16;
  return (u16)r;
}
__device__ __forceinline__ float bf2f(u16 v){
  union { unsigned int u; float f; } x; x.u = ((unsigned int)v) << 16; return x.f;
}

__device__ __forceinline__ void gld16(const void* g, unsigned lds_addr){
  __builtin_amdgcn_global_load_lds(
      (const __attribute__((address_space(1))) unsigned int*)(unsigned long long)g,
      (__attribute__((address_space(3))) unsigned int*)lds_addr,
      16, 0, 0);
}

// ---------------- prep: f32 -> bf16 convert + row norms ----------------
__global__ __launch_bounds__(256) void prep_kernel(
    const float* __restrict__ sup, const float* __restrict__ tgt,
    u16* __restrict__ Abf, u16* __restrict__ Bbf,
    float* __restrict__ nx, float* __restrict__ ny)
{
  int w = (int)((blockIdx.x * blockDim.x + threadIdx.x) >> 6);
  int lane = threadIdx.x & 63;
  if (w >= QT + STF) return;
  bool isQ = (w < QT);
  int row = isQ ? w : (w - QT);
  const float* src = (isQ ? tgt : sup) + (size_t)row * DN + lane * 8;
  f32x4 x0 = *(const f32x4*)src;
  f32x4 x1 = *(const f32x4*)(src + 4);
  float ss = 0.f;
  #pragma unroll
  for (int i = 0; i < 4; ++i) { ss += x0[i]*x0[i]; ss += x1[i]*x1[i]; }
  u16x8 o;
  #pragma unroll
  for (int i = 0; i < 4; ++i) { o[i] = f2bf(x0[i]); o[i+4] = f2bf(x1[i]); }
  u16* dst = (isQ ? Abf : Bbf) + (size_t)row * DN + lane * 8;
  *(u16x8*)dst = o;
  #pragma unroll
  for (int off = 32; off; off >>= 1) ss += __shfl_xor(ss, off);
  if (lane == 0) (isQ ? nx : ny)[row] = sqrtf(ss);
}

// ---------------- fused: gload_lds MFMA GEMM -> LDS ed-tiles -> exp-domain OTAM DP --------
// tile 128x128 frames (8q x 8s) -> 64 pairs x 2 dirs = 128 DP tasks x 512B = 64KB dt.
// GEMM: BK=64 double-buffered A[2][128][64]+B[2][128][64] = 64KB (union w/ dt),
// global_load_lds width-16, counted vmcnt(8), raw s_barrier, read-side XOR swizzle
// (granule ^ (row&7)) with pre-swizzled global source.
__global__ __launch_bounds__(256, 2) void fused_kernel(
    const u16* __restrict__ Abf, const u16* __restrict__ Bbf,
    const float* __restrict__ nx, const float* __restrict__ ny,
    float* __restrict__ out)
{
  __shared__ __align__(128) char smem[65536];
  const int t = threadIdx.x;
  const int m0 = blockIdx.y * 128;   // query-frame base
  const int n0 = blockIdx.x * 128;   // support-frame base
  const int wave = t >> 6, lane = t & 63;
  const int wr = wave >> 1, wc = wave & 1;
  const int lhi = lane >> 4, llo = lane & 15;
  const int x7 = llo & 7;

  const unsigned sbase = (unsigned)(unsigned long long)(void*)smem;

  // staging: wave stages rows [wave*32, wave*32+32) of A and B per K-tile.
  // lane l -> row sub = l>>3, physical granule g = l&7 holds logical granule g^sub.
  const int sub = lane >> 3, gph = lane & 7;
  const u16* pA[4]; const u16* pB[4];
  unsigned ldsA[4], ldsB[4];
  #pragma unroll
  for (int i = 0; i < 4; ++i) {
    int r  = wave*32 + i*8 + sub;
    int lg = gph ^ sub;                 // (r&7)==sub
    pA[i] = Abf + (size_t)(m0 + r) * DN + lg*8;
    pB[i] = Bbf + (size_t)(n0 + r) * DN + lg*8;
    unsigned ro = (unsigned)((wave*32 + i*8) * 128);
    ldsA[i] = __builtin_amdgcn_readfirstlane(sbase + ro);
    ldsB[i] = __builtin_amdgcn_readfirstlane(sbase + 32768u + ro);
  }

  f32x4 acc[4][4] = {};

  auto STAGE = [&](int bufsel, int koff) {
    unsigned bo = (unsigned)(bufsel << 14);
    #pragma unroll
    for (int i = 0; i < 4; ++i) {
      gld16(pA[i] + koff, ldsA[i] + bo);
      gld16(pB[i] + koff, ldsB[i] + bo);
    }
  };

  STAGE(0, 0);
  int buf = 0;
  #pragma unroll 1
  for (int it = 0; it < 8; ++it) {
    if (it < 7) {
      STAGE(buf ^ 1, (it + 1) * 64);
      asm volatile("s_waitcnt vmcnt(8)" ::: "memory");   // current tile's 8 loads done
    } else {
      asm volatile("s_waitcnt vmcnt(0)" ::: "memory");
    }
    __builtin_amdgcn_s_barrier();
    asm volatile("" ::: "memory");
    {
      char* ba = smem + (buf << 14);
      char* bb = smem + 32768 + (buf << 14);
      bf16x8 af[2][4], bfr[2][4];
      #pragma unroll
      for (int kk = 0; kk < 2; ++kk) {
        int po = ((kk*4 + lhi) ^ x7) << 4;   // swizzled 16B granule
        #pragma unroll
        for (int mi = 0; mi < 4; ++mi)
          af[kk][mi] = *(const bf16x8*)(ba + (wr*64 + mi*16 + llo)*128 + po);
        #pragma unroll
        for (int ni = 0; ni < 4; ++ni)
          bfr[kk][ni] = *(const bf16x8*)(bb + (wc*64 + ni*16 + llo)*128 + po);
      }
      #pragma unroll
      for (int kk = 0; kk < 2; ++kk)
        #pragma unroll
        for (int mi = 0; mi < 4; ++mi)
          #pragma unroll
          for (int ni = 0; ni < 4; ++ni)
            acc[mi][ni] = __builtin_amdgcn_mfma_f32_16x16x32_bf16(af[kk][mi], bfr[kk][ni], acc[mi][ni], 0, 0, 0);
    }
    asm volatile("" ::: "memory");
    __builtin_amdgcn_s_barrier();
    buf ^= 1;
  }
  asm volatile("" ::: "memory");

  // ---- epilogue: ed = exp2((acc*rcp(den) - 1)*KEXP), write both orientations ----
  // dt element (l,m) of task T at byte: T*512 + ((l*32 + m*2) ^ ((l&12)<<3) ^ ((T&31)<<4))
  float nxv[4][4];
  #pragma unroll
  for (int mi = 0; mi < 4; ++mi)
    #pragma unroll
    for (int j = 0; j < 4; ++j)
      nxv[mi][j] = nx[m0 + wr*64 + mi*16 + lhi*4 + j];

  #pragma unroll
  for (int ni = 0; ni < 4; ++ni) {
    int gcol = n0 + wc*64 + ni*16 + llo;
    float nyv = ny[gcol];
    int sloc = wc*4 + ni;
    int ts = llo;
    #pragma unroll
    for (int mi = 0; mi < 4; ++mi) {
      int qloc = wr*4 + mi;
      int t0 = (qloc*8 + sloc) * 2;   // dir-0 task
      int t1 = t0 + 1;                // dir-1 task (transposed)
      int swz0 = (t0 & 31) << 4, swz1 = (t1 & 31) << 4;
      u16x4 pk;
      #pragma unroll
      for (int j = 0; j < 4; ++j) {
        int tq = lhi*4 + j;
        float den = nxv[mi][j] * nyv + 0.01f;
        float r = __builtin_amdgcn_rcpf(den);
        float ed = EXP2F(fmaf(acc[mi][ni][j] * r, KEXP, -KEXP));
        u16 e16 = f2bf(ed);
        pk[j] = e16;
        // dir0: element (l=tq, m=ts)
        *(u16*)(smem + t0*512 + ((tq*32 + ts*2) ^ ((tq&12)<<3) ^ swz0)) = e16;
      }
      // dir1: elements (l=ts, m=tq..tq+3), 8B store
      *(u16x4*)(smem + t1*512 + ((ts*32 + lhi*8) ^ ((ts&12)<<3) ^ swz1)) = pk;
    }
  }
  __syncthreads();

  // ---- exp-domain DP, one task per thread (threads 0..127) ----
  if (t < 128) {
    const char* tb = smem + t * 512;
    const int swz = (t & 31) << 4;
    float F[18];
    {
      u16x8 g0 = *(const u16x8*)(tb + (0 ^ swz));
      u16x8 g1 = *(const u16x8*)(tb + (16 ^ swz));
      float c = 1.0f;
      F[0] = 1.0f;
      #pragma unroll
      for (int m = 1; m <= 8; ++m)  { c *= bf2f(g0[m-1]); F[m] = c; }
      #pragma unroll
      for (int m = 9; m <= 16; ++m) { c *= bf2f(g1[m-9]); F[m] = c; }
      F[17] = c;
    }
    // prefetch row 1
    u16x8 h0 = *(const u16x8*)(tb + ((32 ^ ((1&12)<<3)) ^ swz));
    u16x8 h1 = *(const u16x8*)(tb + (((32+16) ^ ((1&12)<<3)) ^ swz));
    float rowc = 1.0f;
    #pragma unroll 1
    for (int l = 1; l < 16; ++l) {
      u16x8 n0v, n1v;
      if (l < 15) {
        int lb = (l+1)*32, lx = ((l+1)&12)<<3;
        n0v = *(const u16x8*)(tb + ((lb ^ lx) ^ swz));
        n1v = *(const u16x8*)(tb + (((lb+16) ^ lx) ^ swz));
      }
      rowc *= K2;
      float pm1 = F[0];      // old F[l-1][0]
      F[0] = rowc;           // cum[l][0] = 0  ->  exp(B_l/lbda)
      {
        float pm = F[1];
        F[1] = bf2f(h0[0]) * (F[0] + pm1*K2 + pm*K2);  // edge m=1: 3 preds
        pm1 = pm;
      }
      #pragma unroll
      for (int m = 2; m <= 8; ++m) {
        float pm = F[m];
        F[m] = bf2f(h0[m-1]) * (F[m-1] + pm1*K2);
        pm1 = pm;
      }
      #pragma unroll
      for (int m = 9; m <= 16; ++m) {
        float pm = F[m];
        F[m] = bf2f(h1[m-9]) * (F[m-1] + pm1*K2);
        pm1 = pm;
      }
      F[17] = F[16] + pm1*K2 + F[17]*K2;  // edge m=17: 3 preds, d_pad=0 -> ed=1
      h0 = n0v; h1 = n1v;
    }
    float res = 15.0f - CLOG * LOG2F(F[17]);
    float other = __shfl_xor(res, 1);
    if (!(t & 1)) {
      int pair = t >> 1, qloc = pair >> 3, sloc = pair & 7;
      out[(size_t)(blockIdx.y*8 + qloc) * SN + blockIdx.x*8 + sloc] = res + other;
    }
  }
}

// ---------------- launch ----------------
extern "C" void kernel_launch(void* const* d_in, const int* in_sizes, int n_in,
                              void* d_out, int out_size, void* d_ws, size_t ws_size,
                              hipStream_t stream)
{
  const float* sup = (const float*)d_in[0];  // [128,16,512]
  const float* tgt = (const float*)d_in[1];  // [512,16,512]
  float* out = (float*)d_out;                // [512,128]
  char* ws = (char*)d_ws;

  u16* Abf = (u16*)(ws);                     // 8192*512*2  = 8,388,608
  u16* Bbf = (u16*)(ws + 8388608);           // 2048*512*2  = 2,097,152
  float* nx = (float*)(ws + 10485760);       // 8192*4
  float* ny = (float*)(ws + 10518528);       // 2048*4

  prep_kernel<<<dim3((QT + STF) / 4), dim3(256), 0, stream>>>(sup, tgt, Abf, Bbf, nx, ny);
  fused_kernel<<<dim3(STF/128, QT/128), dim3(256), 0, stream>>>(Abf, Bbf, nx, ny, out);
}